// Round 4
// baseline (287.981 us; speedup 1.0000x reference)
//
#include <hip/hip_runtime.h>

#define D   256   // columns
#define D4  64    // columns as float4

typedef float f4 __attribute__((ext_vector_type(4)));

// Kernel 1: per-block partial column sums of squares.
// Block = 256 threads = 64 column-groups (float4) x 4 row-phases.
// Normal (caching) loads: we WANT the tail of each chunk resident in L3
// for the scale pass.
__global__ __launch_bounds__(256) void colsq_partial(
    const f4* __restrict__ x4, float* __restrict__ part,
    int rows, int rows_per_block) {
    __shared__ f4 red[256];
    const int t  = threadIdx.x;
    const int cg = t & 63;   // which float4 column group
    const int ro = t >> 6;   // row phase 0..3
    const int r0 = blockIdx.x * rows_per_block;
    const int r1 = min(r0 + rows_per_block, rows);

    f4 acc = (f4)0.f;
    for (int r = r0 + ro; r < r1; r += 4) {
        f4 v = x4[(size_t)r * D4 + cg];   // wave reads 1 KiB contiguous
        acc += v * v;
    }
    red[t] = acc;
    __syncthreads();
    if (t < 64) {
        f4 s = red[t] + red[t + 64] + red[t + 128] + red[t + 192];
        ((f4*)part)[(size_t)blockIdx.x * D4 + t] = s;   // deterministic slot
    }
}

// Kernel 2: parallel reduce of partials. One block per float4 column-group
// (64 blocks x 256 threads). Thread t sums partial rows t, t+256, ... in
// double; deterministic LDS tree-reduce; threads 0..3 write inv values.
__global__ __launch_bounds__(256) void reduce_inv(
    const float* __restrict__ part, float* __restrict__ inv, int nb) {
    __shared__ double red[4][256];
    const int g = blockIdx.x;    // float4 column group 0..63
    const int t = threadIdx.x;
    const f4* part4 = (const f4*)part;

    double sx = 0.0, sy = 0.0, sz = 0.0, sw = 0.0;
    for (int b = t; b < nb; b += 256) {
        f4 v = part4[(size_t)b * D4 + g];
        sx += (double)v.x; sy += (double)v.y;
        sz += (double)v.z; sw += (double)v.w;
    }
    red[0][t] = sx; red[1][t] = sy; red[2][t] = sz; red[3][t] = sw;
    __syncthreads();
    for (int ofs = 128; ofs > 0; ofs >>= 1) {
        if (t < ofs) {
            red[0][t] += red[0][t + ofs];
            red[1][t] += red[1][t + ofs];
            red[2][t] += red[2][t + ofs];
            red[3][t] += red[3][t + ofs];
        }
        __syncthreads();
    }
    if (t < 4) inv[g * 4 + t] = (float)(1.0 / sqrt(red[t][0]));
}

// Kernel 3: out = x * inv[col]. SAME block->chunk mapping as colsq_partial,
// iterated in REVERSE row order so each block re-reads its most-recently-
// cached (L3-resident) tail first. NORMAL cached loads for x (harvest the
// L3 hits); non-temporal stores for out (don't evict x's resident lines).
__global__ __launch_bounds__(256) void scale_cols(
    const f4* __restrict__ x4, const float* __restrict__ inv,
    f4* __restrict__ out4, int rows, int rows_per_block) {
    __shared__ float sinv[D];
    if (threadIdx.x < D) sinv[threadIdx.x] = inv[threadIdx.x];
    __syncthreads();
    const int t  = threadIdx.x;
    const int cg = t & 63;
    const int ro = t >> 6;
    const int r0 = blockIdx.x * rows_per_block;
    const int r1 = min(r0 + rows_per_block, rows);
    const f4 s = ((const f4*)sinv)[cg];

    const int nq = (r1 - r0 + 3) >> 2;           // quads in this chunk
    for (int k = nq - 1; k >= 0; --k) {
        const int r = r0 + k * 4 + ro;
        if (r < r1) {
            const size_t idx = (size_t)r * D4 + cg;
            f4 v = x4[idx];
            __builtin_nontemporal_store(v * s, &out4[idx]);
        }
    }
}

extern "C" void kernel_launch(void* const* d_in, const int* in_sizes, int n_in,
                              void* d_out, int out_size, void* d_ws, size_t ws_size,
                              hipStream_t stream) {
    const float* x = (const float*)d_in[0];
    float* out = (float*)d_out;
    const size_t n = (size_t)in_sizes[0];      // 524288 * 256
    const int rows = (int)(n / D);

    // Adaptive partial-block count so partials + inv fit in d_ws.
    int nb = 2048;
    while (nb > 64 && ((size_t)nb * D + D) * sizeof(float) > ws_size) nb >>= 1;

    float* part = (float*)d_ws;
    float* inv  = part + (size_t)nb * D;

    const int rows_per_block = (rows + nb - 1) / nb;

    colsq_partial<<<nb, 256, 0, stream>>>((const f4*)x, part, rows, rows_per_block);
    reduce_inv<<<D4, 256, 0, stream>>>(part, inv, nb);
    scale_cols<<<nb, 256, 0, stream>>>((const f4*)x, inv, (f4*)out, rows, rows_per_block);
}